// Round 1
// baseline (187.535 us; speedup 1.0000x reference)
//
#include <hip/hip_runtime.h>
#include <math.h>

// Turb2dPDE, MFMA fp16-split pipeline. Per block b:
//   Y = x * C2        (col-DFT first: x rows feed A-frags straight from global)
//   Out = F1 * Y      (row-DFT; row-reordered tables so j=32/c=32 land in fixup slots)
//   X = streams x G   (Hermitian-halved inverse, c-major)
//   psiT = Hc x X     (transposed psi; stencil reads are bank-free)
// All inter-stage LDS layouts are exactly the next stage's fragment layout ->
// every epilogue store is a contiguous half4 (b64); all LDS strides 2-way-bank (free).
// Static tables stored wave-linear in global (1KB contiguous per wave b128 load).
//
// R1: 512-thread blocks (8 waves) on the SAME single batch + same 40448B LDS.
//     4 blocks/CU x 8 waves = 32 waves/CU (was 16) -> 2x latency hiding.
//     S4a split into 18 half-positions ((c-tile, s-tile, Xr|Xi)); other stages
//     just re-striped across 8 waves. VGPRs must stay <=64 (launch_bounds(512,8)).

typedef _Float16 half8 __attribute__((ext_vector_type(8)));
typedef _Float16 half4 __attribute__((ext_vector_type(4)));
typedef float floatx4 __attribute__((ext_vector_type(4)));

#define WPI 0.09666439165562847f   // 2*pi/65

// half-unit offsets in ws
#define H_TB1 0        // [20 chunks][512] S1-B: rows [cos c0..31 | sin c0..31 | cos32,sin32], fold k=0
#define H_TA2 10240    // [20 chunks][512] S2-A: rows [-cos j0..31 | sin j0..31 | -cos32,sin32], fold m=0
#define H_TG  20480    // [12 chunks][512] S4a-B: Gr/Gi [s][j], s>32 -> 0
#define H_TH  26624    // [12 chunks][512] S4b-A: Hc/Hs [p][c], incl 1/4225 & x2(c>=1), p>32 -> 0
// float-unit offsets
#define F_GR32 16384   // [48] cos(w*32*s)
#define F_GI32 16432   // [48] sin(w*32*s)
#define F_HC32 16480   // [48] 2inv*cos(w*32*p)
#define F_HS32 16528   // [48] 2inv*sin(w*32*p)
#define F_SE   16576   // [8][1089]

__device__ __forceinline__ float trig65(int t, int isSin) {
    return isSin ? sinf(WPI * (float)t) : cosf(WPI * (float)t);
}

__global__ void setup_tables(float* __restrict__ ws, const float* __restrict__ domain) {
    int idx = blockIdx.x * 256 + threadIdx.x;
    _Float16* tbH = (_Float16*)ws;
    const float inv = 1.0f / 4225.0f;
    if (idx < 32768) {
        float v = 0.0f;
        int part;
        if (idx < 10240) {                  // TB1 (B-layout): chunk=(ni*2+kc)*2+part
            int chunk = idx >> 9, within = idx & 511;
            part = chunk & 1; int kc = (chunk >> 1) & 1, ni = chunk >> 2;
            int l2 = within >> 3, j = within & 7;
            int row = 16 * ni + (l2 & 15);
            int k = 32 * kc + 8 * (l2 >> 4) + j;
            if (row < 66) {
                int c = (row < 32) ? row : (row < 64 ? row - 32 : 32);
                int isS = (row < 32) ? 0 : (row < 64 ? 1 : row - 64);
                v = trig65((k * c) % 65, isS);
                if (k == 0) v += trig65((64 * c) % 65, isS);
            }
        } else if (idx < 20480) {           // TA2 (A-layout): chunk=(mi*2+kc)*2+part
            int i2 = idx - 10240;
            int chunk = i2 >> 9, within = i2 & 511;
            part = chunk & 1; int kc = (chunk >> 1) & 1, mi = chunk >> 2;
            int l2 = within >> 3, j = within & 7;
            int row = 16 * mi + (l2 & 15);
            int m = 32 * kc + 8 * (l2 >> 4) + j;
            if (row < 66) {
                int jr = (row < 32) ? row : (row < 64 ? row - 32 : 32);
                int isS = (row < 32) ? 0 : (row < 64 ? 1 : row - 64);
                float s = isS ? 1.0f : -1.0f;   // P rows = -cos, Q rows = +sin
                v = s * trig65((jr * m) % 65, isS);
                if (m == 0) v += s * trig65((jr * 64) % 65, isS);
            }
        } else if (idx < 26624) {           // TG: chunk=(si*2+g)*2+part
            int i2 = idx - 20480;
            int chunk = i2 >> 9, within = i2 & 511;
            part = chunk & 1; int g = (chunk >> 1) & 1, si = chunk >> 2;
            int l2 = within >> 3, j = within & 7;
            int s = 16 * si + (l2 & 15);
            int jj = 8 * (l2 >> 4) + j;
            if (s <= 32) v = trig65((s * jj) % 65, g);
        } else {                            // TH: chunk=(pi*2+h)*2+part
            int i2 = idx - 26624;
            int chunk = i2 >> 9, within = i2 & 511;
            part = chunk & 1; int h = (chunk >> 1) & 1, pi2 = chunk >> 2;
            int l2 = within >> 3, j = within & 7;
            int p = 16 * pi2 + (l2 & 15);
            int c = 8 * (l2 >> 4) + j;
            if (p <= 32) {
                if (c == 0) v = h ? 0.0f : inv;
                else v = 2.0f * inv * trig65((c * p) % 65, h);
            }
        }
        _Float16 hh = (_Float16)v;
        tbH[idx] = part ? (_Float16)(v - (float)hh) : hh;
    } else if (idx < 32960) {               // fp32 aux
        int i2 = idx - 32768;
        int grp = i2 / 48, s = i2 - grp * 48;
        float v = 0.0f;
        if (s <= 32) {
            int t = (32 * s) % 65;
            float cs = cosf(WPI * t), sn = sinf(WPI * t);
            v = (grp == 0) ? cs : (grp == 1) ? sn : (grp == 2) ? 2.0f * inv * cs : 2.0f * inv * sn;
        }
        ws[F_GR32 + i2] = v;
    } else if (idx < 41672) {               // Se
        int i2 = idx - 32960;
        int e2 = i2 / 1089, rem = i2 - e2 * 1089;
        int a = rem / 33, b2 = rem - a * 33;
        const float DX0 = 0.04908738521234052f;
        float fdx = domain[e2] * DX0;
        float tt = 6.283185307179586f / (65.0f * fdx);
        float s2v = tt * tt;
        ws[F_SE + i2] = -1.0f / (1e-12f + s2v * (float)(a * a + b2 * b2));
    }
}

#define MFMA16(A, B, C) __builtin_amdgcn_mfma_f32_16x16x32_f16((A), (B), (C), 0, 0, 0)

__global__ __launch_bounds__(512, 8)
void turb_kernel(const float* __restrict__ y0, const int* __restrict__ env,
                 const float* __restrict__ params, const float* __restrict__ domain,
                 const float* __restrict__ ws, float* __restrict__ out) {
    // LDS arenas (bytes):
    //  A @0     : Yt [66][136]h (S1->S2, overread rows to 79 lands in B, harmless/discarded)
    //             then Xr[64][72]@0 Xi@9216 X32r@18432 X32i@18688 (S4a->S4b)
    //  B @18944 : ST 4x[33][72] + S32[4][33]@+19008 (S2->S4a, +overread slack)
    //             then psiT[64][65] f32 (S4b->stencil)
    __shared__ __align__(16) char lds_raw[40448];
    _Float16* Yt  = (_Float16*)lds_raw;
    _Float16* Xr  = (_Float16*)lds_raw;
    _Float16* Xi  = (_Float16*)(lds_raw + 9216);
    float*    X32r = (float*)(lds_raw + 18432);
    float*    X32i = (float*)(lds_raw + 18688);
    _Float16* ST  = (_Float16*)(lds_raw + 18944);
    float*    S32 = (float*)(lds_raw + 18944 + 19008);
    float*    psiT = (float*)(lds_raw + 18944);

    const int b = blockIdx.x, tid = threadIdx.x;
    const int wid = tid >> 6, lane = tid & 63, n16 = lane & 15, q = lane >> 4;
    const int e = env[b];
    const _Float16* tbH = (const _Float16*)ws;
    const float* tf = ws;
    const float* Se = tf + F_SE + e * 1089;
    const float* x0 = y0 + (size_t)b * 4096;

    // ---- S1: Yt[c'][m] = sum_k x[m][k]*TB1[c'][k]
    // 8 waves: mi = wid&3 owns 16 m-rows; low waves do ni 0..2, high waves ni 3..4.
    {
        const int mi = wid & 3;
        half8 Ah[2], Al[2];
        const float* xrow = x0 + (16 * mi + n16) * 64 + 8 * q;
        #pragma unroll
        for (int kc = 0; kc < 2; kc++) {
            float4 v0 = *(const float4*)(xrow + 32 * kc);
            float4 v1 = *(const float4*)(xrow + 32 * kc + 4);
            float vv[8] = {v0.x, v0.y, v0.z, v0.w, v1.x, v1.y, v1.z, v1.w};
            #pragma unroll
            for (int u = 0; u < 8; u++) {
                _Float16 h = (_Float16)vv[u];
                Ah[kc][u] = h; Al[kc][u] = (_Float16)(vv[u] - (float)h);
            }
        }
        const int niBeg = (wid & 4) ? 3 : 0;
        const int niEnd = (wid & 4) ? 5 : 3;
        for (int ni = niBeg; ni < niEnd; ni++) {
            floatx4 acc = {0.f, 0.f, 0.f, 0.f};
            #pragma unroll
            for (int kc = 0; kc < 2; kc++) {
                half8 Bh = *(const half8*)(tbH + H_TB1 + ((ni * 2 + kc) * 2 + 0) * 512 + lane * 8);
                half8 Bl = *(const half8*)(tbH + H_TB1 + ((ni * 2 + kc) * 2 + 1) * 512 + lane * 8);
                acc = MFMA16(Ah[kc], Bh, acc);
                acc = MFMA16(Ah[kc], Bl, acc);
                acc = MFMA16(Al[kc], Bh, acc);
            }
            int cp = 16 * ni + n16;
            if (ni < 4 || n16 < 2) {
                half4 hh, ll;
                #pragma unroll
                for (int i = 0; i < 4; i++) {
                    _Float16 h = (_Float16)acc[i];
                    hh[i] = h; ll[i] = (_Float16)(acc[i] - (float)h);
                }
                *(half4*)(Yt + cp * 136 + 16 * mi + 4 * q) = hh;
                *(half4*)(Yt + cp * 136 + 64 + 16 * mi + 4 * q) = ll;
            }
        }
    }
    __syncthreads();

    // ---- S2: Out[j'][c'] = sum_m TA2[j'][m]*Yt[c'][m] -> 4 streams ST[sid][cc][jj] + S32
    for (int pos = wid; pos < 25; pos += 8) {
        int mi = pos / 5, ni = pos - 5 * mi;
        floatx4 acc = {0.f, 0.f, 0.f, 0.f};
        #pragma unroll
        for (int kc = 0; kc < 2; kc++) {
            half8 Ah = *(const half8*)(tbH + H_TA2 + ((mi * 2 + kc) * 2 + 0) * 512 + lane * 8);
            half8 Al = *(const half8*)(tbH + H_TA2 + ((mi * 2 + kc) * 2 + 1) * 512 + lane * 8);
            half8 Bh = *(const half8*)(Yt + (16 * ni + n16) * 136 + 32 * kc + 8 * q);
            half8 Bl = *(const half8*)(Yt + (16 * ni + n16) * 136 + 64 + 32 * kc + 8 * q);
            acc = MFMA16(Ah, Bh, acc);
            acc = MFMA16(Ah, Bl, acc);
            acc = MFMA16(Al, Bh, acc);
        }
        if ((ni < 4) || (n16 < 2)) {
            int cp = 16 * ni + n16;
            int cc = (ni == 4) ? 32 : (cp & 31);
            int isS = (ni == 4) ? n16 : (ni >> 1);
            if (mi < 4) {
                int isQ = mi >> 1;
                int sid = isQ ? (isS ? 3 : 1) : (isS ? 2 : 0);
                int jjb = 16 * (mi & 1) + 4 * q;
                half4 hh, ll;
                #pragma unroll
                for (int i = 0; i < 4; i++) {
                    float S = Se[cc * 33 + jjb + i];
                    float v = 2.0f * S * acc[i];
                    if (sid == 2) v = -v;
                    _Float16 h = (_Float16)v;
                    hh[i] = h; ll[i] = (_Float16)(v - (float)h);
                }
                _Float16* sb = ST + sid * 2376 + cc * 72 + jjb;
                *(half4*)sb = hh;
                *(half4*)(sb + 32) = ll;
            } else if (q == 0) {            // rows 64 (P32) / 65 (Q32) -> S32
                float S = Se[cc * 33 + 32];
                #pragma unroll
                for (int i = 0; i < 2; i++) {
                    int sid = i ? (isS ? 3 : 1) : (isS ? 2 : 0);
                    float v = 2.0f * S * acc[i];
                    if (sid == 2) v = -v;
                    S32[sid * 33 + cc] = v;
                }
            }
        }
    }
    __syncthreads();

    // ---- j=0 fixup: upr0=umr0=S(A+D)/..., (0,0)->0
    if (tid < 33) {
        int c = tid;
        float v0[4];
        #pragma unroll
        for (int sid = 0; sid < 4; sid++)
            v0[sid] = (float)ST[sid * 2376 + c * 72] + (float)ST[sid * 2376 + c * 72 + 32];
        float pr = 0.5f * (v0[0] + v0[3]), pi = 0.5f * (v0[1] + v0[2]);
        if (c == 0) { pr = 0.f; pi = 0.f; }
        float outs[4] = {pr, pi, pi, pr};
        #pragma unroll
        for (int sid = 0; sid < 4; sid++) {
            _Float16 h = (_Float16)outs[sid];
            ST[sid * 2376 + c * 72] = h;
            ST[sid * 2376 + c * 72 + 32] = (_Float16)(outs[sid] - (float)h);
        }
    }
    __syncthreads();

    // ---- S4a: X[c-rows][s-cols]: A = streams [c][j], B = G [s][j]; j=32 via S32 fixup
    // 18 half-positions: (ci, si, g) with g=0 -> streams {0,1} -> Xr, g=1 -> {2,3} -> Xi.
    for (int pos = wid; pos < 18; pos += 8) {
        int ci = pos / 6, rem = pos - 6 * ci;
        int si = rem >> 1, g = rem & 1;
        int arow = (16 * ci + n16) * 72 + 8 * q;
        const _Float16* st0 = ST + (2 * g) * 2376;
        half8 A0h = *(const half8*)(st0 + arow),        A0l = *(const half8*)(st0 + arow + 32);
        half8 A1h = *(const half8*)(st0 + 2376 + arow), A1l = *(const half8*)(st0 + 2376 + arow + 32);
        half8 Grh = *(const half8*)(tbH + H_TG + ((si * 2 + 0) * 2 + 0) * 512 + lane * 8);
        half8 Grl = *(const half8*)(tbH + H_TG + ((si * 2 + 0) * 2 + 1) * 512 + lane * 8);
        half8 Gih = *(const half8*)(tbH + H_TG + ((si * 2 + 1) * 2 + 0) * 512 + lane * 8);
        half8 Gil = *(const half8*)(tbH + H_TG + ((si * 2 + 1) * 2 + 1) * 512 + lane * 8);
        floatx4 aA = {0.f,0.f,0.f,0.f}, aB = aA;
        aA = MFMA16(A0h, Grh, aA); aA = MFMA16(A0h, Grl, aA); aA = MFMA16(A0l, Grh, aA);
        aB = MFMA16(A1h, Gih, aB); aB = MFMA16(A1h, Gil, aB); aB = MFMA16(A1l, Gih, aB);
        int s = 16 * si + n16;
        float ga = tf[F_GR32 + s], gi2 = tf[F_GI32 + s];
        bool sval = (si < 2) || (n16 == 0);     // s <= 32
        _Float16* Xo = g ? Xi : Xr;
        float* X32o = g ? X32i : X32r;
        const float sgn = g ? 1.0f : -1.0f;     // g=0: xP=av-bv,xM=av+bv ; g=1: xP=av+bv,xM=av-bv
        if (ci < 2) {
            half4 hP, lP, hM, lM;
            #pragma unroll
            for (int i = 0; i < 4; i++) {
                int c = 16 * ci + 4 * q + i;
                float u0 = S32[(2 * g) * 33 + c], u1 = S32[(2 * g + 1) * 33 + c];
                float av = aA[i] + ga * u0, bv = aB[i] + gi2 * u1;
                float xP = av + sgn * bv;
                float xM = av - sgn * bv;
                _Float16 h;
                h = (_Float16)xP; hP[i] = h; lP[i] = (_Float16)(xP - (float)h);
                h = (_Float16)xM; hM[i] = h; lM[i] = (_Float16)(xM - (float)h);
            }
            int cb = 16 * ci + 4 * q;
            if (sval) {
                *(half4*)(Xo + s * 72 + cb) = hP;  *(half4*)(Xo + s * 72 + 32 + cb) = lP;
                if (s >= 2) {
                    int sm = 65 - s;
                    *(half4*)(Xo + sm * 72 + cb) = hM;  *(half4*)(Xo + sm * 72 + 32 + cb) = lM;
                }
            }
        } else if (q == 0 && sval) {            // c = 32 column -> fp32
            float u0 = S32[(2 * g) * 33 + 32], u1 = S32[(2 * g + 1) * 33 + 32];
            float av = aA[0] + ga * u0, bv = aB[0] + gi2 * u1;
            X32o[s] = av + sgn * bv;
            if (s >= 2) X32o[65 - s] = av - sgn * bv;
        }
    }
    __syncthreads();

    // ---- S4b: psiT[p][r] = E-F, psiT[65-p][r] = E+F;  A = Hc/Hs, B = Xr/Xi; c=32 via X32
    for (int pos = wid; pos < 12; pos += 8) {
        int ri = pos / 3, pti = pos - 3 * ri;
        int brow = (16 * ri + n16) * 72 + 8 * q;
        half8 Brh = *(const half8*)(Xr + brow), Brl = *(const half8*)(Xr + brow + 32);
        half8 Bih = *(const half8*)(Xi + brow), Bil = *(const half8*)(Xi + brow + 32);
        half8 Hch = *(const half8*)(tbH + H_TH + ((pti * 2 + 0) * 2 + 0) * 512 + lane * 8);
        half8 Hcl = *(const half8*)(tbH + H_TH + ((pti * 2 + 0) * 2 + 1) * 512 + lane * 8);
        half8 Hsh = *(const half8*)(tbH + H_TH + ((pti * 2 + 1) * 2 + 0) * 512 + lane * 8);
        half8 Hsl = *(const half8*)(tbH + H_TH + ((pti * 2 + 1) * 2 + 1) * 512 + lane * 8);
        floatx4 aE = {0.f,0.f,0.f,0.f}, aF = aE;
        aE = MFMA16(Hch, Brh, aE); aE = MFMA16(Hch, Brl, aE); aE = MFMA16(Hcl, Brh, aE);
        aF = MFMA16(Hsh, Bih, aF); aF = MFMA16(Hsh, Bil, aF); aF = MFMA16(Hsl, Bih, aF);
        int r = 16 * ri + n16;
        float xr32 = X32r[r], xi32 = X32i[r];
        #pragma unroll
        for (int i = 0; i < 4; i++) {
            int p = 16 * pti + 4 * q + i;
            if (pti < 2 || (q == 0 && i == 0)) {
                float E = aE[i] + xr32 * tf[F_HC32 + p];
                float F = aF[i] + xi32 * tf[F_HS32 + p];
                psiT[p * 65 + r] = E - F;
                if (p >= 2) psiT[(65 - p) * 65 + r] = E + F;
            }
        }
    }
    __syncthreads();

    // ---- stencil: lane=c, rows 8*wid..+7; x from global (coalesced rows), psi from psiT
    {
        const int c = lane;
        const int cm1 = (c + 63) & 63, cp1 = (c + 1) & 63;
        const float mu = params[2 * e];
        const float DX0 = 0.04908738521234052f;
        const float fdx = domain[e] * DX0;
        const float fdx2 = fdx * fdx;
        const float inv12 = 1.0f / (12.0f * fdx2);
        const float invf = mu / fdx2;
        float* o = out + (size_t)b * 4096;
        const int r0 = wid * 8;
        int rm = (r0 + 63) & 63;
        float xLm = x0[rm * 64 + cm1], xCm = x0[rm * 64 + c], xRm = x0[rm * 64 + cp1];
        float pLm = psiT[cm1 * 65 + rm], pCm = psiT[c * 65 + rm], pRm = psiT[cp1 * 65 + rm];
        float xLc = x0[r0 * 64 + cm1], xCc = x0[r0 * 64 + c], xRc = x0[r0 * 64 + cp1];
        float pLc = psiT[cm1 * 65 + r0], pCc = psiT[c * 65 + r0], pRc = psiT[cp1 * 65 + r0];
        #pragma unroll
        for (int it = 0; it < 8; it++) {
            int r = r0 + it;
            int rn = (r + 1) & 63;
            float xLp = x0[rn * 64 + cm1], xCp = x0[rn * 64 + c], xRp = x0[rn * 64 + cp1];
            float pLp = psiT[cm1 * 65 + rn], pCp = psiT[c * 65 + rn], pRp = psiT[cp1 * 65 + rn];
            float J1 = (pCp - pCm) * (xRc - xLc) - (pRc - pLc) * (xCp - xCm);
            float J2 = xRc * (pRp - pRm) - xLc * (pLp - pLm) - xCp * (pRp - pLp) + xCm * (pRm - pLm);
            float J3 = xRp * (pCp - pRc) - xLm * (pLc - pCm) - xLp * (pCp - pLc) + xRm * (pRc - pCm);
            float lap = xCm + xLc - 4.f * xCc + xRc + xLp + xCp;
            o[r * 64 + c] = -(J1 + J2 + J3) * inv12 + lap * invf;
            xLm = xLc; xCm = xCc; xRm = xRc; pLm = pLc; pCm = pCc; pRm = pRc;
            xLc = xLp; xCc = xCp; xRc = xRp; pLc = pLp; pCc = pCp; pRc = pRp;
        }
    }
}

extern "C" void kernel_launch(void* const* d_in, const int* in_sizes, int n_in,
                              void* d_out, int out_size, void* d_ws, size_t ws_size,
                              hipStream_t stream) {
    const float* y0     = (const float*)d_in[1];
    const int*   env    = (const int*)d_in[2];
    const float* params = (const float*)d_in[4];
    const float* domain = (const float*)d_in[5];
    float* out = (float*)d_out;
    float* ws  = (float*)d_ws;   // 101,152 B used

    setup_tables<<<dim3(163), dim3(256), 0, stream>>>(ws, domain);
    turb_kernel<<<dim3(4096), dim3(512), 0, stream>>>(y0, env, params, domain, ws, out);
}

// Round 3
// 187.499 us; speedup vs baseline: 1.0002x; 1.0002x over previous
//
#include <hip/hip_runtime.h>
#include <math.h>

// Turb2dPDE, MFMA fp16-split pipeline. Per block b:
//   Y = x * C2        (col-DFT first: x rows feed A-frags straight from global)
//   Out = F1 * Y      (row-DFT; row-reordered tables so j=32/c=32 land in fixup slots)
//   X = streams x G   (Hermitian-halved inverse, c-major)
//   psiT = Hc x X     (transposed psi; stencil reads are bank-free)
// R1: 512-thread blocks, 4 blocks/CU x 8 waves = 32 waves/CU.
// R2: wave-uniform values forced to SGPR (readfirstlane on wid/e) so all stage
//     addressing is SALU not VALU; stencil uses constant-offset addressing;
//     S2 prefetches next-pos A-tables across the MFMA cluster.
// R3: same as R2 minus two risk items (unaligned floatx4 Se load; uninit
//     prefetch regs on final iteration) after an infra-level bench failure.

typedef _Float16 half8 __attribute__((ext_vector_type(8)));
typedef _Float16 half4 __attribute__((ext_vector_type(4)));
typedef float floatx4 __attribute__((ext_vector_type(4)));

#define WPI 0.09666439165562847f   // 2*pi/65

// half-unit offsets in ws
#define H_TB1 0        // [20 chunks][512] S1-B: rows [cos c0..31 | sin c0..31 | cos32,sin32], fold k=0
#define H_TA2 10240    // [20 chunks][512] S2-A: rows [-cos j0..31 | sin j0..31 | -cos32,sin32], fold m=0
#define H_TG  20480    // [12 chunks][512] S4a-B: Gr/Gi [s][j], s>32 -> 0
#define H_TH  26624    // [12 chunks][512] S4b-A: Hc/Hs [p][c], incl 1/4225 & x2(c>=1), p>32 -> 0
// float-unit offsets
#define F_GR32 16384   // [48] cos(w*32*s)
#define F_GI32 16432   // [48] sin(w*32*s)
#define F_HC32 16480   // [48] 2inv*cos(w*32*p)
#define F_HS32 16528   // [48] 2inv*sin(w*32*p)
#define F_SE   16576   // [8][1089]

__device__ __forceinline__ float trig65(int t, int isSin) {
    return isSin ? sinf(WPI * (float)t) : cosf(WPI * (float)t);
}

__global__ void setup_tables(float* __restrict__ ws, const float* __restrict__ domain) {
    int idx = blockIdx.x * 256 + threadIdx.x;
    _Float16* tbH = (_Float16*)ws;
    const float inv = 1.0f / 4225.0f;
    if (idx < 32768) {
        float v = 0.0f;
        int part;
        if (idx < 10240) {                  // TB1 (B-layout): chunk=(ni*2+kc)*2+part
            int chunk = idx >> 9, within = idx & 511;
            part = chunk & 1; int kc = (chunk >> 1) & 1, ni = chunk >> 2;
            int l2 = within >> 3, j = within & 7;
            int row = 16 * ni + (l2 & 15);
            int k = 32 * kc + 8 * (l2 >> 4) + j;
            if (row < 66) {
                int c = (row < 32) ? row : (row < 64 ? row - 32 : 32);
                int isS = (row < 32) ? 0 : (row < 64 ? 1 : row - 64);
                v = trig65((k * c) % 65, isS);
                if (k == 0) v += trig65((64 * c) % 65, isS);
            }
        } else if (idx < 20480) {           // TA2 (A-layout): chunk=(mi*2+kc)*2+part
            int i2 = idx - 10240;
            int chunk = i2 >> 9, within = i2 & 511;
            part = chunk & 1; int kc = (chunk >> 1) & 1, mi = chunk >> 2;
            int l2 = within >> 3, j = within & 7;
            int row = 16 * mi + (l2 & 15);
            int m = 32 * kc + 8 * (l2 >> 4) + j;
            if (row < 66) {
                int jr = (row < 32) ? row : (row < 64 ? row - 32 : 32);
                int isS = (row < 32) ? 0 : (row < 64 ? 1 : row - 64);
                float s = isS ? 1.0f : -1.0f;   // P rows = -cos, Q rows = +sin
                v = s * trig65((jr * m) % 65, isS);
                if (m == 0) v += s * trig65((jr * 64) % 65, isS);
            }
        } else if (idx < 26624) {           // TG: chunk=(si*2+g)*2+part
            int i2 = idx - 20480;
            int chunk = i2 >> 9, within = i2 & 511;
            part = chunk & 1; int g = (chunk >> 1) & 1, si = chunk >> 2;
            int l2 = within >> 3, j = within & 7;
            int s = 16 * si + (l2 & 15);
            int jj = 8 * (l2 >> 4) + j;
            if (s <= 32) v = trig65((s * jj) % 65, g);
        } else {                            // TH: chunk=(pi*2+h)*2+part
            int i2 = idx - 26624;
            int chunk = i2 >> 9, within = i2 & 511;
            part = chunk & 1; int h = (chunk >> 1) & 1, pi2 = chunk >> 2;
            int l2 = within >> 3, j = within & 7;
            int p = 16 * pi2 + (l2 & 15);
            int c = 8 * (l2 >> 4) + j;
            if (p <= 32) {
                if (c == 0) v = h ? 0.0f : inv;
                else v = 2.0f * inv * trig65((c * p) % 65, h);
            }
        }
        _Float16 hh = (_Float16)v;
        tbH[idx] = part ? (_Float16)(v - (float)hh) : hh;
    } else if (idx < 32960) {               // fp32 aux
        int i2 = idx - 32768;
        int grp = i2 / 48, s = i2 - grp * 48;
        float v = 0.0f;
        if (s <= 32) {
            int t = (32 * s) % 65;
            float cs = cosf(WPI * t), sn = sinf(WPI * t);
            v = (grp == 0) ? cs : (grp == 1) ? sn : (grp == 2) ? 2.0f * inv * cs : 2.0f * inv * sn;
        }
        ws[F_GR32 + i2] = v;
    } else if (idx < 41672) {               // Se
        int i2 = idx - 32960;
        int e2 = i2 / 1089, rem = i2 - e2 * 1089;
        int a = rem / 33, b2 = rem - a * 33;
        const float DX0 = 0.04908738521234052f;
        float fdx = domain[e2] * DX0;
        float tt = 6.283185307179586f / (65.0f * fdx);
        float s2v = tt * tt;
        ws[F_SE + i2] = -1.0f / (1e-12f + s2v * (float)(a * a + b2 * b2));
    }
}

#define MFMA16(A, B, C) __builtin_amdgcn_mfma_f32_16x16x32_f16((A), (B), (C), 0, 0, 0)

__global__ __launch_bounds__(512, 8)
void turb_kernel(const float* __restrict__ y0, const int* __restrict__ env,
                 const float* __restrict__ params, const float* __restrict__ domain,
                 const float* __restrict__ ws, float* __restrict__ out) {
    // LDS arenas (bytes):
    //  A @0     : Yt [66][136]h (S1->S2)
    //             then Xr[64][72]@0 Xi@9216 X32r@18432 X32i@18688 (S4a->S4b)
    //  B @18944 : ST 4x[33][72] + S32[4][33]@+19008 (S2->S4a)
    //             then psiT[64][65] f32 (S4b->stencil)
    __shared__ __align__(16) char lds_raw[40448];
    _Float16* Yt  = (_Float16*)lds_raw;
    _Float16* Xr  = (_Float16*)lds_raw;
    _Float16* Xi  = (_Float16*)(lds_raw + 9216);
    float*    X32r = (float*)(lds_raw + 18432);
    float*    X32i = (float*)(lds_raw + 18688);
    _Float16* ST  = (_Float16*)(lds_raw + 18944);
    float*    S32 = (float*)(lds_raw + 18944 + 19008);
    float*    psiT = (float*)(lds_raw + 18944);

    const int b = blockIdx.x, tid = threadIdx.x;
    // wid/e are wave-uniform: force to SGPR so all derived addressing is SALU.
    const int wid = __builtin_amdgcn_readfirstlane(tid >> 6);
    const int lane = tid & 63, n16 = lane & 15, q = lane >> 4;
    const int lane8 = lane * 8;
    const int e = __builtin_amdgcn_readfirstlane(env[b]);
    const _Float16* tbH = (const _Float16*)ws;
    const float* tf = ws;
    const float* Se = tf + F_SE + e * 1089;
    const float* x0 = y0 + (size_t)b * 4096;

    // stencil uniforms hoisted: latency hidden under S1..S4b
    const float DX0 = 0.04908738521234052f;
    const float mu = params[2 * e];
    const float fdx = domain[e] * DX0;
    const float fdx2 = fdx * fdx;
    const float inv12 = 1.0f / (12.0f * fdx2);
    const float invf = mu / fdx2;

    // ---- S1: Yt[c'][m] = sum_k x[m][k]*TB1[c'][k]
    // mi = wid&3 owns 16 m-rows; low waves do ni 0..2, high waves ni 3..4.
    {
        const int mi = wid & 3;
        half8 Ah[2], Al[2];
        const float* xrow = x0 + (16 * mi + n16) * 64 + 8 * q;
        #pragma unroll
        for (int kc = 0; kc < 2; kc++) {
            float4 v0 = *(const float4*)(xrow + 32 * kc);
            float4 v1 = *(const float4*)(xrow + 32 * kc + 4);
            float vv[8] = {v0.x, v0.y, v0.z, v0.w, v1.x, v1.y, v1.z, v1.w};
            #pragma unroll
            for (int u = 0; u < 8; u++) {
                _Float16 h = (_Float16)vv[u];
                Ah[kc][u] = h; Al[kc][u] = (_Float16)(vv[u] - (float)h);
            }
        }
        const int niBeg = (wid & 4) ? 3 : 0;
        const int niEnd = (wid & 4) ? 5 : 3;
        for (int ni = niBeg; ni < niEnd; ni++) {
            const _Float16* tb = tbH + H_TB1 + ni * 2048 + lane8;   // SGPR base + lane voffset
            half8 B0h = *(const half8*)(tb);
            half8 B0l = *(const half8*)(tb + 512);
            half8 B1h = *(const half8*)(tb + 1024);
            half8 B1l = *(const half8*)(tb + 1536);
            floatx4 acc = {0.f, 0.f, 0.f, 0.f};
            acc = MFMA16(Ah[0], B0h, acc); acc = MFMA16(Ah[0], B0l, acc); acc = MFMA16(Al[0], B0h, acc);
            acc = MFMA16(Ah[1], B1h, acc); acc = MFMA16(Ah[1], B1l, acc); acc = MFMA16(Al[1], B1h, acc);
            int cp = 16 * ni + n16;
            if (ni < 4 || n16 < 2) {
                half4 hh, ll;
                #pragma unroll
                for (int i = 0; i < 4; i++) {
                    _Float16 h = (_Float16)acc[i];
                    hh[i] = h; ll[i] = (_Float16)(acc[i] - (float)h);
                }
                *(half4*)(Yt + cp * 136 + 16 * mi + 4 * q) = hh;
                *(half4*)(Yt + cp * 136 + 64 + 16 * mi + 4 * q) = ll;
            }
        }
    }
    __syncthreads();

    // ---- S2: Out[j'][c'] = sum_m TA2[j'][m]*Yt[c'][m] -> 4 streams ST + S32
    // A-tables (global, L2-latency) prefetched one pos ahead across the MFMA cluster.
    {
        int pos = wid;
        half8 Ah0, Al0, Ah1, Al1;
        {
            const _Float16* ta = tbH + H_TA2 + (pos / 5) * 2048 + lane8;
            Ah0 = *(const half8*)(ta);
            Al0 = *(const half8*)(ta + 512);
            Ah1 = *(const half8*)(ta + 1024);
            Al1 = *(const half8*)(ta + 1536);
        }
        while (pos < 25) {
            const int mi = pos / 5, ni = pos - 5 * mi;
            const int npos = pos + 8;
            half8 nAh0 = {}, nAl0 = {}, nAh1 = {}, nAl1 = {};
            if (npos < 25) {
                const _Float16* ta = tbH + H_TA2 + (npos / 5) * 2048 + lane8;
                nAh0 = *(const half8*)(ta);
                nAl0 = *(const half8*)(ta + 512);
                nAh1 = *(const half8*)(ta + 1024);
                nAl1 = *(const half8*)(ta + 1536);
            }
            const _Float16* yrow = Yt + (16 * ni + n16) * 136 + 8 * q;
            half8 Bh0 = *(const half8*)(yrow);
            half8 Bl0 = *(const half8*)(yrow + 64);
            half8 Bh1 = *(const half8*)(yrow + 32);
            half8 Bl1 = *(const half8*)(yrow + 96);
            floatx4 acc = {0.f, 0.f, 0.f, 0.f};
            acc = MFMA16(Ah0, Bh0, acc); acc = MFMA16(Ah0, Bl0, acc); acc = MFMA16(Al0, Bh0, acc);
            acc = MFMA16(Ah1, Bh1, acc); acc = MFMA16(Ah1, Bl1, acc); acc = MFMA16(Al1, Bh1, acc);
            if ((ni < 4) || (n16 < 2)) {
                int cp = 16 * ni + n16;
                int cc = (ni == 4) ? 32 : (cp & 31);
                int isS = (ni == 4) ? n16 : (ni >> 1);
                if (mi < 4) {
                    int isQ = mi >> 1;
                    int sid = isQ ? (isS ? 3 : 1) : (isS ? 2 : 0);
                    int jjb = 16 * (mi & 1) + 4 * q;
                    float ssg = (sid == 2) ? -2.0f : 2.0f;
                    half4 hh, ll;
                    #pragma unroll
                    for (int i = 0; i < 4; i++) {
                        float v = ssg * Se[cc * 33 + jjb + i] * acc[i];
                        _Float16 h = (_Float16)v;
                        hh[i] = h; ll[i] = (_Float16)(v - (float)h);
                    }
                    _Float16* sb = ST + sid * 2376 + cc * 72 + jjb;
                    *(half4*)sb = hh;
                    *(half4*)(sb + 32) = ll;
                } else if (q == 0) {            // rows 64 (P32) / 65 (Q32) -> S32
                    float S = Se[cc * 33 + 32];
                    #pragma unroll
                    for (int i = 0; i < 2; i++) {
                        int sid = i ? (isS ? 3 : 1) : (isS ? 2 : 0);
                        float v = 2.0f * S * acc[i];
                        if (sid == 2) v = -v;
                        S32[sid * 33 + cc] = v;
                    }
                }
            }
            Ah0 = nAh0; Al0 = nAl0; Ah1 = nAh1; Al1 = nAl1;
            pos = npos;
        }
    }
    __syncthreads();

    // ---- j=0 fixup: upr0=umr0=S(A+D)/..., (0,0)->0
    if (tid < 33) {
        int c = tid;
        float v0[4];
        #pragma unroll
        for (int sid = 0; sid < 4; sid++)
            v0[sid] = (float)ST[sid * 2376 + c * 72] + (float)ST[sid * 2376 + c * 72 + 32];
        float pr = 0.5f * (v0[0] + v0[3]), pi = 0.5f * (v0[1] + v0[2]);
        if (c == 0) { pr = 0.f; pi = 0.f; }
        float outs[4] = {pr, pi, pi, pr};
        #pragma unroll
        for (int sid = 0; sid < 4; sid++) {
            _Float16 h = (_Float16)outs[sid];
            ST[sid * 2376 + c * 72] = h;
            ST[sid * 2376 + c * 72 + 32] = (_Float16)(outs[sid] - (float)h);
        }
    }
    __syncthreads();

    // ---- S4a: X[c-rows][s-cols]: A = streams [c][j], B = G [s][j]; j=32 via S32 fixup
    // 18 half-positions: (ci, si, g) with g=0 -> streams {0,1} -> Xr, g=1 -> {2,3} -> Xi.
    for (int pos = wid; pos < 18; pos += 8) {
        const int ci = pos / 6, rem = pos - 6 * ci;
        const int si = rem >> 1, g = rem & 1;
        const _Float16* st0 = ST + (2 * g) * 2376 + (16 * ci + n16) * 72 + 8 * q;
        half8 A0h = *(const half8*)(st0),        A0l = *(const half8*)(st0 + 32);
        half8 A1h = *(const half8*)(st0 + 2376), A1l = *(const half8*)(st0 + 2376 + 32);
        const _Float16* tg = tbH + H_TG + si * 2048 + lane8;
        half8 Grh = *(const half8*)(tg);
        half8 Grl = *(const half8*)(tg + 512);
        half8 Gih = *(const half8*)(tg + 1024);
        half8 Gil = *(const half8*)(tg + 1536);
        floatx4 aA = {0.f,0.f,0.f,0.f}, aB = aA;
        aA = MFMA16(A0h, Grh, aA); aA = MFMA16(A0h, Grl, aA); aA = MFMA16(A0l, Grh, aA);
        aB = MFMA16(A1h, Gih, aB); aB = MFMA16(A1h, Gil, aB); aB = MFMA16(A1l, Gih, aB);
        int s = 16 * si + n16;
        float ga = tf[F_GR32 + s], gi2 = tf[F_GI32 + s];
        bool sval = (si < 2) || (n16 == 0);     // s <= 32
        _Float16* Xo = g ? Xi : Xr;
        float* X32o = g ? X32i : X32r;
        const float sgn = g ? 1.0f : -1.0f;     // g=0: xP=av-bv,xM=av+bv ; g=1: xP=av+bv,xM=av-bv
        if (ci < 2) {
            half4 hP, lP, hM, lM;
            #pragma unroll
            for (int i = 0; i < 4; i++) {
                int c = 16 * ci + 4 * q + i;
                float u0 = S32[(2 * g) * 33 + c], u1 = S32[(2 * g + 1) * 33 + c];
                float av = aA[i] + ga * u0, bv = aB[i] + gi2 * u1;
                float xP = av + sgn * bv;
                float xM = av - sgn * bv;
                _Float16 h;
                h = (_Float16)xP; hP[i] = h; lP[i] = (_Float16)(xP - (float)h);
                h = (_Float16)xM; hM[i] = h; lM[i] = (_Float16)(xM - (float)h);
            }
            int cb = 16 * ci + 4 * q;
            if (sval) {
                *(half4*)(Xo + s * 72 + cb) = hP;  *(half4*)(Xo + s * 72 + 32 + cb) = lP;
                if (s >= 2) {
                    int sm = 65 - s;
                    *(half4*)(Xo + sm * 72 + cb) = hM;  *(half4*)(Xo + sm * 72 + 32 + cb) = lM;
                }
            }
        } else if (q == 0 && sval) {            // c = 32 column -> fp32
            float u0 = S32[(2 * g) * 33 + 32], u1 = S32[(2 * g + 1) * 33 + 32];
            float av = aA[0] + ga * u0, bv = aB[0] + gi2 * u1;
            X32o[s] = av + sgn * bv;
            if (s >= 2) X32o[65 - s] = av - sgn * bv;
        }
    }
    __syncthreads();

    // ---- S4b: psiT[p][r] = E-F, psiT[65-p][r] = E+F;  A = Hc/Hs, B = Xr/Xi; c=32 via X32
    for (int pos = wid; pos < 12; pos += 8) {
        const int ri = pos / 3, pti = pos - 3 * ri;
        const int brow = (16 * ri + n16) * 72 + 8 * q;
        half8 Brh = *(const half8*)(Xr + brow), Brl = *(const half8*)(Xr + brow + 32);
        half8 Bih = *(const half8*)(Xi + brow), Bil = *(const half8*)(Xi + brow + 32);
        const _Float16* th = tbH + H_TH + pti * 2048 + lane8;
        half8 Hch = *(const half8*)(th);
        half8 Hcl = *(const half8*)(th + 512);
        half8 Hsh = *(const half8*)(th + 1024);
        half8 Hsl = *(const half8*)(th + 1536);
        floatx4 aE = {0.f,0.f,0.f,0.f}, aF = aE;
        aE = MFMA16(Hch, Brh, aE); aE = MFMA16(Hch, Brl, aE); aE = MFMA16(Hcl, Brh, aE);
        aF = MFMA16(Hsh, Bih, aF); aF = MFMA16(Hsh, Bil, aF); aF = MFMA16(Hsl, Bih, aF);
        int r = 16 * ri + n16;
        float xr32 = X32r[r], xi32 = X32i[r];
        if (pti < 2) {
            const int pb = 16 * pti + 4 * q;
            float* pp = psiT + pb * 65 + r;
            float* pm = psiT + (65 - pb) * 65 + r;
            #pragma unroll
            for (int i = 0; i < 4; i++) {
                float E = aE[i] + xr32 * tf[F_HC32 + pb + i];
                float F = aF[i] + xi32 * tf[F_HS32 + pb + i];
                pp[i * 65] = E - F;
                if (pb + i >= 2) pm[-i * 65] = E + F;
            }
        } else if (q == 0) {                    // p == 32
            float E = aE[0] + xr32 * tf[F_HC32 + 32];
            float F = aF[0] + xi32 * tf[F_HS32 + 32];
            psiT[32 * 65 + r] = E - F;
            psiT[33 * 65 + r] = E + F;
        }
    }
    __syncthreads();

    // ---- stencil: lane=c, rows 8*wid..+7; all steady-state addresses are
    // fixed base + compile-time-constant offset (wraps are uniform specials).
    {
        const int c = lane;
        const int cm1 = (c + 63) & 63, cp1 = (c + 1) & 63;
        const int r0 = wid * 8;
        const float* xL = x0 + r0 * 64 + cm1;
        const float* xC = x0 + r0 * 64 + c;
        const float* xR = x0 + r0 * 64 + cp1;
        const float* pL = psiT + cm1 * 65 + r0;
        const float* pC = psiT + c * 65 + r0;
        const float* pR = psiT + cp1 * 65 + r0;
        float* ob = out + (size_t)b * 4096 + r0 * 64 + c;
        const int mo = (wid == 0) ? 63 : -1;    // prev-row offset (wraps for wid 0)
        float xLm = xL[mo * 64], xCm = xC[mo * 64], xRm = xR[mo * 64];
        float pLm = pL[mo], pCm = pC[mo], pRm = pR[mo];
        float xLc = xL[0], xCc = xC[0], xRc = xR[0];
        float pLc = pL[0], pCc = pC[0], pRc = pR[0];
        #pragma unroll
        for (int it = 0; it < 8; it++) {
            int ro = it + 1;
            if (it == 7 && wid == 7) ro = -56;  // next-row wrap (uniform, last iter only)
            float xLp = xL[ro * 64], xCp = xC[ro * 64], xRp = xR[ro * 64];
            float pLp = pL[ro], pCp = pC[ro], pRp = pR[ro];
            float J1 = (pCp - pCm) * (xRc - xLc) - (pRc - pLc) * (xCp - xCm);
            float J2 = xRc * (pRp - pRm) - xLc * (pLp - pLm) - xCp * (pRp - pLp) + xCm * (pRm - pLm);
            float J3 = xRp * (pCp - pRc) - xLm * (pLc - pCm) - xLp * (pCp - pLc) + xRm * (pRc - pCm);
            float lap = xCm + xLc - 4.f * xCc + xRc + xLp + xCp;
            ob[it * 64] = -(J1 + J2 + J3) * inv12 + lap * invf;
            xLm = xLc; xCm = xCc; xRm = xRc; pLm = pLc; pCm = pCc; pRm = pRc;
            xLc = xLp; xCc = xCp; xRc = xRp; pLc = pLp; pCc = pCp; pRc = pRp;
        }
    }
}

extern "C" void kernel_launch(void* const* d_in, const int* in_sizes, int n_in,
                              void* d_out, int out_size, void* d_ws, size_t ws_size,
                              hipStream_t stream) {
    const float* y0     = (const float*)d_in[1];
    const int*   env    = (const int*)d_in[2];
    const float* params = (const float*)d_in[4];
    const float* domain = (const float*)d_in[5];
    float* out = (float*)d_out;
    float* ws  = (float*)d_ws;   // 101,152 B used

    setup_tables<<<dim3(163), dim3(256), 0, stream>>>(ws, domain);
    turb_kernel<<<dim3(4096), dim3(512), 0, stream>>>(y0, env, params, domain, ws, out);
}

// Round 4
// 185.282 us; speedup vs baseline: 1.0122x; 1.0120x over previous
//
#include <hip/hip_runtime.h>
#include <math.h>

// Turb2dPDE, MFMA fp16-split pipeline. Per block b:
//   Y = x * C2        (col-DFT first: x rows feed A-frags straight from global)
//   Out = F1 * Y      (row-DFT; row-reordered tables so j=32/c=32 land in fixup slots)
//   X = streams x G   (Hermitian-halved inverse, c-major)
//   psiT = Hc x X     (transposed psi; stencil reads are bank-free)
// R1: 512-thread blocks, 4 blocks/CU x 8 waves = 32 waves/CU.
// R2/R3: wave-uniform wid/e -> SGPR addressing; const-offset stencil; S2 prefetch.
// R4: LDS/VMEM op-count reduction (theory: LDS pipe ~60% busy is the limiter):
//     S32 restride 33->36 -> S4a reads 2x ds_read_b128 instead of 8x b32;
//     Se re-layout [8][33]+[8][33][32] (same 101,152 B) -> S2 epilogue 1x dwordx4;
//     S4b HC/HS table reads as dwordx4; setup_tables uses native __sinf/__cosf.

typedef _Float16 half8 __attribute__((ext_vector_type(8)));
typedef _Float16 half4 __attribute__((ext_vector_type(4)));
typedef float floatx4 __attribute__((ext_vector_type(4)));

#define WPI 0.09666439165562847f   // 2*pi/65

// half-unit offsets in ws
#define H_TB1 0        // [20 chunks][512] S1-B: rows [cos c0..31 | sin c0..31 | cos32,sin32], fold k=0
#define H_TA2 10240    // [20 chunks][512] S2-A: rows [-cos j0..31 | sin j0..31 | -cos32,sin32], fold m=0
#define H_TG  20480    // [12 chunks][512] S4a-B: Gr/Gi [s][j], s>32 -> 0
#define H_TH  26624    // [12 chunks][512] S4b-A: Hc/Hs [p][c], incl 1/4225 & x2(c>=1), p>32 -> 0
// float-unit offsets
#define F_GR32 16384   // [48] cos(w*32*s)
#define F_GI32 16432   // [48] sin(w*32*s)
#define F_HC32 16480   // [48] 2inv*cos(w*32*p)
#define F_HS32 16528   // [48] 2inv*sin(w*32*p)
#define F_SE   16576   // [8][33] jj=32 col, then [8][33][32] grid (16B-aligned rows)
#define F_SEG  (F_SE + 264)   // grid part base

__device__ __forceinline__ float trig65(int t, int isSin) {
    return isSin ? __sinf(WPI * (float)t) : __cosf(WPI * (float)t);
}

__global__ void setup_tables(float* __restrict__ ws, const float* __restrict__ domain) {
    int idx = blockIdx.x * 256 + threadIdx.x;
    _Float16* tbH = (_Float16*)ws;
    const float inv = 1.0f / 4225.0f;
    if (idx < 32768) {
        float v = 0.0f;
        int part;
        if (idx < 10240) {                  // TB1 (B-layout): chunk=(ni*2+kc)*2+part
            int chunk = idx >> 9, within = idx & 511;
            part = chunk & 1; int kc = (chunk >> 1) & 1, ni = chunk >> 2;
            int l2 = within >> 3, j = within & 7;
            int row = 16 * ni + (l2 & 15);
            int k = 32 * kc + 8 * (l2 >> 4) + j;
            if (row < 66) {
                int c = (row < 32) ? row : (row < 64 ? row - 32 : 32);
                int isS = (row < 32) ? 0 : (row < 64 ? 1 : row - 64);
                v = trig65((k * c) % 65, isS);
                if (k == 0) v += trig65((64 * c) % 65, isS);
            }
        } else if (idx < 20480) {           // TA2 (A-layout): chunk=(mi*2+kc)*2+part
            int i2 = idx - 10240;
            int chunk = i2 >> 9, within = i2 & 511;
            part = chunk & 1; int kc = (chunk >> 1) & 1, mi = chunk >> 2;
            int l2 = within >> 3, j = within & 7;
            int row = 16 * mi + (l2 & 15);
            int m = 32 * kc + 8 * (l2 >> 4) + j;
            if (row < 66) {
                int jr = (row < 32) ? row : (row < 64 ? row - 32 : 32);
                int isS = (row < 32) ? 0 : (row < 64 ? 1 : row - 64);
                float s = isS ? 1.0f : -1.0f;   // P rows = -cos, Q rows = +sin
                v = s * trig65((jr * m) % 65, isS);
                if (m == 0) v += s * trig65((jr * 64) % 65, isS);
            }
        } else if (idx < 26624) {           // TG: chunk=(si*2+g)*2+part
            int i2 = idx - 20480;
            int chunk = i2 >> 9, within = i2 & 511;
            part = chunk & 1; int g = (chunk >> 1) & 1, si = chunk >> 2;
            int l2 = within >> 3, j = within & 7;
            int s = 16 * si + (l2 & 15);
            int jj = 8 * (l2 >> 4) + j;
            if (s <= 32) v = trig65((s * jj) % 65, g);
        } else {                            // TH: chunk=(pi*2+h)*2+part
            int i2 = idx - 26624;
            int chunk = i2 >> 9, within = i2 & 511;
            part = chunk & 1; int h = (chunk >> 1) & 1, pi2 = chunk >> 2;
            int l2 = within >> 3, j = within & 7;
            int p = 16 * pi2 + (l2 & 15);
            int c = 8 * (l2 >> 4) + j;
            if (p <= 32) {
                if (c == 0) v = h ? 0.0f : inv;
                else v = 2.0f * inv * trig65((c * p) % 65, h);
            }
        }
        _Float16 hh = (_Float16)v;
        tbH[idx] = part ? (_Float16)(v - (float)hh) : hh;
    } else if (idx < 32960) {               // fp32 aux
        int i2 = idx - 32768;
        int grp = i2 / 48, s = i2 - grp * 48;
        float v = 0.0f;
        if (s <= 32) {
            int t = (32 * s) % 65;
            float cs = __cosf(WPI * t), sn = __sinf(WPI * t);
            v = (grp == 0) ? cs : (grp == 1) ? sn : (grp == 2) ? 2.0f * inv * cs : 2.0f * inv * sn;
        }
        ws[F_GR32 + i2] = v;
    } else if (idx < 41672) {               // Se: [8][33] jj=32 col, then [8][33][32] grid
        int i2 = idx - 32960;
        const float DX0 = 0.04908738521234052f;
        int e2, a, b2;
        if (i2 < 264) {                     // jj=32 column
            e2 = i2 / 33; a = i2 - e2 * 33; b2 = 32;
        } else {                            // grid rows of 32
            int i3 = i2 - 264;
            e2 = i3 / 1056;
            int rem = i3 - e2 * 1056;
            a = rem >> 5; b2 = rem & 31;
        }
        float fdx = domain[e2] * DX0;
        float tt = 6.283185307179586f / (65.0f * fdx);
        float s2v = tt * tt;
        ws[F_SE + i2] = -1.0f / (1e-12f + s2v * (float)(a * a + b2 * b2));
    }
}

#define MFMA16(A, B, C) __builtin_amdgcn_mfma_f32_16x16x32_f16((A), (B), (C), 0, 0, 0)

__global__ __launch_bounds__(512, 8)
void turb_kernel(const float* __restrict__ y0, const int* __restrict__ env,
                 const float* __restrict__ params, const float* __restrict__ domain,
                 const float* __restrict__ ws, float* __restrict__ out) {
    // LDS arenas (bytes):
    //  A @0     : Yt [66][136]h (S1->S2)
    //             then Xr[64][72]@0 Xi@9216 X32r@18432 X32i@18688 (S4a->S4b)
    //  B @18944 : ST 4x[33][72] + S32[4][36]@+19008 (S2->S4a; stride 36 for b128)
    //             then psiT[64][65] f32 (S4b->stencil)
    __shared__ __align__(16) char lds_raw[40448];
    _Float16* Yt  = (_Float16*)lds_raw;
    _Float16* Xr  = (_Float16*)lds_raw;
    _Float16* Xi  = (_Float16*)(lds_raw + 9216);
    float*    X32r = (float*)(lds_raw + 18432);
    float*    X32i = (float*)(lds_raw + 18688);
    _Float16* ST  = (_Float16*)(lds_raw + 18944);
    float*    S32 = (float*)(lds_raw + 18944 + 19008);   // [4][36] f32, 16B-aligned
    float*    psiT = (float*)(lds_raw + 18944);

    const int b = blockIdx.x, tid = threadIdx.x;
    // wid/e are wave-uniform: force to SGPR so all derived addressing is SALU.
    const int wid = __builtin_amdgcn_readfirstlane(tid >> 6);
    const int lane = tid & 63, n16 = lane & 15, q = lane >> 4;
    const int lane8 = lane * 8;
    const int e = __builtin_amdgcn_readfirstlane(env[b]);
    const _Float16* tbH = (const _Float16*)ws;
    const float* tf = ws;
    const float* Se3 = tf + F_SE + e * 33;        // jj=32 column
    const float* Seg = tf + F_SEG + e * 1056;     // [33][32] grid, rows 16B-aligned
    const float* x0 = y0 + (size_t)b * 4096;

    // stencil uniforms hoisted: latency hidden under S1..S4b
    const float DX0 = 0.04908738521234052f;
    const float mu = params[2 * e];
    const float fdx = domain[e] * DX0;
    const float fdx2 = fdx * fdx;
    const float inv12 = 1.0f / (12.0f * fdx2);
    const float invf = mu / fdx2;

    // ---- S1: Yt[c'][m] = sum_k x[m][k]*TB1[c'][k]
    // mi = wid&3 owns 16 m-rows; low waves do ni 0..2, high waves ni 3..4.
    {
        const int mi = wid & 3;
        half8 Ah[2], Al[2];
        const float* xrow = x0 + (16 * mi + n16) * 64 + 8 * q;
        #pragma unroll
        for (int kc = 0; kc < 2; kc++) {
            float4 v0 = *(const float4*)(xrow + 32 * kc);
            float4 v1 = *(const float4*)(xrow + 32 * kc + 4);
            float vv[8] = {v0.x, v0.y, v0.z, v0.w, v1.x, v1.y, v1.z, v1.w};
            #pragma unroll
            for (int u = 0; u < 8; u++) {
                _Float16 h = (_Float16)vv[u];
                Ah[kc][u] = h; Al[kc][u] = (_Float16)(vv[u] - (float)h);
            }
        }
        const int niBeg = (wid & 4) ? 3 : 0;
        const int niEnd = (wid & 4) ? 5 : 3;
        for (int ni = niBeg; ni < niEnd; ni++) {
            const _Float16* tb = tbH + H_TB1 + ni * 2048 + lane8;   // SGPR base + lane voffset
            half8 B0h = *(const half8*)(tb);
            half8 B0l = *(const half8*)(tb + 512);
            half8 B1h = *(const half8*)(tb + 1024);
            half8 B1l = *(const half8*)(tb + 1536);
            floatx4 acc = {0.f, 0.f, 0.f, 0.f};
            acc = MFMA16(Ah[0], B0h, acc); acc = MFMA16(Ah[0], B0l, acc); acc = MFMA16(Al[0], B0h, acc);
            acc = MFMA16(Ah[1], B1h, acc); acc = MFMA16(Ah[1], B1l, acc); acc = MFMA16(Al[1], B1h, acc);
            int cp = 16 * ni + n16;
            if (ni < 4 || n16 < 2) {
                half4 hh, ll;
                #pragma unroll
                for (int i = 0; i < 4; i++) {
                    _Float16 h = (_Float16)acc[i];
                    hh[i] = h; ll[i] = (_Float16)(acc[i] - (float)h);
                }
                *(half4*)(Yt + cp * 136 + 16 * mi + 4 * q) = hh;
                *(half4*)(Yt + cp * 136 + 64 + 16 * mi + 4 * q) = ll;
            }
        }
    }
    __syncthreads();

    // ---- S2: Out[j'][c'] = sum_m TA2[j'][m]*Yt[c'][m] -> 4 streams ST + S32
    // A-tables (global, L2-latency) prefetched one pos ahead across the MFMA cluster.
    {
        int pos = wid;
        half8 Ah0, Al0, Ah1, Al1;
        {
            const _Float16* ta = tbH + H_TA2 + (pos / 5) * 2048 + lane8;
            Ah0 = *(const half8*)(ta);
            Al0 = *(const half8*)(ta + 512);
            Ah1 = *(const half8*)(ta + 1024);
            Al1 = *(const half8*)(ta + 1536);
        }
        while (pos < 25) {
            const int mi = pos / 5, ni = pos - 5 * mi;
            const int npos = pos + 8;
            half8 nAh0 = {}, nAl0 = {}, nAh1 = {}, nAl1 = {};
            if (npos < 25) {
                const _Float16* ta = tbH + H_TA2 + (npos / 5) * 2048 + lane8;
                nAh0 = *(const half8*)(ta);
                nAl0 = *(const half8*)(ta + 512);
                nAh1 = *(const half8*)(ta + 1024);
                nAl1 = *(const half8*)(ta + 1536);
            }
            const _Float16* yrow = Yt + (16 * ni + n16) * 136 + 8 * q;
            half8 Bh0 = *(const half8*)(yrow);
            half8 Bl0 = *(const half8*)(yrow + 64);
            half8 Bh1 = *(const half8*)(yrow + 32);
            half8 Bl1 = *(const half8*)(yrow + 96);
            floatx4 acc = {0.f, 0.f, 0.f, 0.f};
            acc = MFMA16(Ah0, Bh0, acc); acc = MFMA16(Ah0, Bl0, acc); acc = MFMA16(Al0, Bh0, acc);
            acc = MFMA16(Ah1, Bh1, acc); acc = MFMA16(Ah1, Bl1, acc); acc = MFMA16(Al1, Bh1, acc);
            if ((ni < 4) || (n16 < 2)) {
                int cp = 16 * ni + n16;
                int cc = (ni == 4) ? 32 : (cp & 31);
                int isS = (ni == 4) ? n16 : (ni >> 1);
                if (mi < 4) {
                    int isQ = mi >> 1;
                    int sid = isQ ? (isS ? 3 : 1) : (isS ? 2 : 0);
                    int jjb = 16 * (mi & 1) + 4 * q;
                    floatx4 Sv = *(const floatx4*)(Seg + cc * 32 + jjb);   // 16B-aligned dwordx4
                    float ssg = (sid == 2) ? -2.0f : 2.0f;
                    half4 hh, ll;
                    #pragma unroll
                    for (int i = 0; i < 4; i++) {
                        float v = ssg * Sv[i] * acc[i];
                        _Float16 h = (_Float16)v;
                        hh[i] = h; ll[i] = (_Float16)(v - (float)h);
                    }
                    _Float16* sb = ST + sid * 2376 + cc * 72 + jjb;
                    *(half4*)sb = hh;
                    *(half4*)(sb + 32) = ll;
                } else if (q == 0) {            // rows 64 (P32) / 65 (Q32) -> S32
                    float S = Se3[cc];
                    #pragma unroll
                    for (int i = 0; i < 2; i++) {
                        int sid = i ? (isS ? 3 : 1) : (isS ? 2 : 0);
                        float v = 2.0f * S * acc[i];
                        if (sid == 2) v = -v;
                        S32[sid * 36 + cc] = v;
                    }
                }
            }
            Ah0 = nAh0; Al0 = nAl0; Ah1 = nAh1; Al1 = nAl1;
            pos = npos;
        }
    }
    __syncthreads();

    // ---- j=0 fixup: upr0=umr0=S(A+D)/..., (0,0)->0
    if (tid < 33) {
        int c = tid;
        float v0[4];
        #pragma unroll
        for (int sid = 0; sid < 4; sid++)
            v0[sid] = (float)ST[sid * 2376 + c * 72] + (float)ST[sid * 2376 + c * 72 + 32];
        float pr = 0.5f * (v0[0] + v0[3]), pi = 0.5f * (v0[1] + v0[2]);
        if (c == 0) { pr = 0.f; pi = 0.f; }
        float outs[4] = {pr, pi, pi, pr};
        #pragma unroll
        for (int sid = 0; sid < 4; sid++) {
            _Float16 h = (_Float16)outs[sid];
            ST[sid * 2376 + c * 72] = h;
            ST[sid * 2376 + c * 72 + 32] = (_Float16)(outs[sid] - (float)h);
        }
    }
    __syncthreads();

    // ---- S4a: X[c-rows][s-cols]: A = streams [c][j], B = G [s][j]; j=32 via S32 fixup
    // 18 half-positions: (ci, si, g) with g=0 -> streams {0,1} -> Xr, g=1 -> {2,3} -> Xi.
    for (int pos = wid; pos < 18; pos += 8) {
        const int ci = pos / 6, rem = pos - 6 * ci;
        const int si = rem >> 1, g = rem & 1;
        const _Float16* st0 = ST + (2 * g) * 2376 + (16 * ci + n16) * 72 + 8 * q;
        half8 A0h = *(const half8*)(st0),        A0l = *(const half8*)(st0 + 32);
        half8 A1h = *(const half8*)(st0 + 2376), A1l = *(const half8*)(st0 + 2376 + 32);
        const _Float16* tg = tbH + H_TG + si * 2048 + lane8;
        half8 Grh = *(const half8*)(tg);
        half8 Grl = *(const half8*)(tg + 512);
        half8 Gih = *(const half8*)(tg + 1024);
        half8 Gil = *(const half8*)(tg + 1536);
        floatx4 aA = {0.f,0.f,0.f,0.f}, aB = aA;
        aA = MFMA16(A0h, Grh, aA); aA = MFMA16(A0h, Grl, aA); aA = MFMA16(A0l, Grh, aA);
        aB = MFMA16(A1h, Gih, aB); aB = MFMA16(A1h, Gil, aB); aB = MFMA16(A1l, Gih, aB);
        int s = 16 * si + n16;
        float ga = tf[F_GR32 + s], gi2 = tf[F_GI32 + s];
        bool sval = (si < 2) || (n16 == 0);     // s <= 32
        _Float16* Xo = g ? Xi : Xr;
        float* X32o = g ? X32i : X32r;
        const float sgn = g ? 1.0f : -1.0f;     // g=0: xP=av-bv,xM=av+bv ; g=1: xP=av+bv,xM=av-bv
        if (ci < 2) {
            const int cb = 16 * ci + 4 * q;
            floatx4 U0 = *(const floatx4*)(S32 + (2 * g) * 36 + cb);       // ds_read_b128
            floatx4 U1 = *(const floatx4*)(S32 + (2 * g + 1) * 36 + cb);   // ds_read_b128
            half4 hP, lP, hM, lM;
            #pragma unroll
            for (int i = 0; i < 4; i++) {
                float av = aA[i] + ga * U0[i], bv = aB[i] + gi2 * U1[i];
                float xP = av + sgn * bv;
                float xM = av - sgn * bv;
                _Float16 h;
                h = (_Float16)xP; hP[i] = h; lP[i] = (_Float16)(xP - (float)h);
                h = (_Float16)xM; hM[i] = h; lM[i] = (_Float16)(xM - (float)h);
            }
            if (sval) {
                *(half4*)(Xo + s * 72 + cb) = hP;  *(half4*)(Xo + s * 72 + 32 + cb) = lP;
                if (s >= 2) {
                    int sm = 65 - s;
                    *(half4*)(Xo + sm * 72 + cb) = hM;  *(half4*)(Xo + sm * 72 + 32 + cb) = lM;
                }
            }
        } else if (q == 0 && sval) {            // c = 32 column -> fp32
            float u0 = S32[(2 * g) * 36 + 32], u1 = S32[(2 * g + 1) * 36 + 32];
            float av = aA[0] + ga * u0, bv = aB[0] + gi2 * u1;
            X32o[s] = av + sgn * bv;
            if (s >= 2) X32o[65 - s] = av - sgn * bv;
        }
    }
    __syncthreads();

    // ---- S4b: psiT[p][r] = E-F, psiT[65-p][r] = E+F;  A = Hc/Hs, B = Xr/Xi; c=32 via X32
    for (int pos = wid; pos < 12; pos += 8) {
        const int ri = pos / 3, pti = pos - 3 * ri;
        const int brow = (16 * ri + n16) * 72 + 8 * q;
        half8 Brh = *(const half8*)(Xr + brow), Brl = *(const half8*)(Xr + brow + 32);
        half8 Bih = *(const half8*)(Xi + brow), Bil = *(const half8*)(Xi + brow + 32);
        const _Float16* th = tbH + H_TH + pti * 2048 + lane8;
        half8 Hch = *(const half8*)(th);
        half8 Hcl = *(const half8*)(th + 512);
        half8 Hsh = *(const half8*)(th + 1024);
        half8 Hsl = *(const half8*)(th + 1536);
        floatx4 aE = {0.f,0.f,0.f,0.f}, aF = aE;
        aE = MFMA16(Hch, Brh, aE); aE = MFMA16(Hch, Brl, aE); aE = MFMA16(Hcl, Brh, aE);
        aF = MFMA16(Hsh, Bih, aF); aF = MFMA16(Hsh, Bil, aF); aF = MFMA16(Hsl, Bih, aF);
        int r = 16 * ri + n16;
        float xr32 = X32r[r], xi32 = X32i[r];
        if (pti < 2) {
            const int pb = 16 * pti + 4 * q;
            floatx4 Hc4 = *(const floatx4*)(tf + F_HC32 + pb);   // aligned dwordx4
            floatx4 Hs4 = *(const floatx4*)(tf + F_HS32 + pb);
            float* pp = psiT + pb * 65 + r;
            float* pm = psiT + (65 - pb) * 65 + r;
            #pragma unroll
            for (int i = 0; i < 4; i++) {
                float E = aE[i] + xr32 * Hc4[i];
                float F = aF[i] + xi32 * Hs4[i];
                pp[i * 65] = E - F;
                if (pb + i >= 2) pm[-i * 65] = E + F;
            }
        } else if (q == 0) {                    // p == 32
            float E = aE[0] + xr32 * tf[F_HC32 + 32];
            float F = aF[0] + xi32 * tf[F_HS32 + 32];
            psiT[32 * 65 + r] = E - F;
            psiT[33 * 65 + r] = E + F;
        }
    }
    __syncthreads();

    // ---- stencil: lane=c, rows 8*wid..+7; all steady-state addresses are
    // fixed base + compile-time-constant offset (wraps are uniform specials).
    {
        const int c = lane;
        const int cm1 = (c + 63) & 63, cp1 = (c + 1) & 63;
        const int r0 = wid * 8;
        const float* xL = x0 + r0 * 64 + cm1;
        const float* xC = x0 + r0 * 64 + c;
        const float* xR = x0 + r0 * 64 + cp1;
        const float* pL = psiT + cm1 * 65 + r0;
        const float* pC = psiT + c * 65 + r0;
        const float* pR = psiT + cp1 * 65 + r0;
        float* ob = out + (size_t)b * 4096 + r0 * 64 + c;
        const int mo = (wid == 0) ? 63 : -1;    // prev-row offset (wraps for wid 0)
        float xLm = xL[mo * 64], xCm = xC[mo * 64], xRm = xR[mo * 64];
        float pLm = pL[mo], pCm = pC[mo], pRm = pR[mo];
        float xLc = xL[0], xCc = xC[0], xRc = xR[0];
        float pLc = pL[0], pCc = pC[0], pRc = pR[0];
        #pragma unroll
        for (int it = 0; it < 8; it++) {
            int ro = it + 1;
            if (it == 7 && wid == 7) ro = -56;  // next-row wrap (uniform, last iter only)
            float xLp = xL[ro * 64], xCp = xC[ro * 64], xRp = xR[ro * 64];
            float pLp = pL[ro], pCp = pC[ro], pRp = pR[ro];
            float J1 = (pCp - pCm) * (xRc - xLc) - (pRc - pLc) * (xCp - xCm);
            float J2 = xRc * (pRp - pRm) - xLc * (pLp - pLm) - xCp * (pRp - pLp) + xCm * (pRm - pLm);
            float J3 = xRp * (pCp - pRc) - xLm * (pLc - pCm) - xLp * (pCp - pLc) + xRm * (pRc - pCm);
            float lap = xCm + xLc - 4.f * xCc + xRc + xLp + xCp;
            ob[it * 64] = -(J1 + J2 + J3) * inv12 + lap * invf;
            xLm = xLc; xCm = xCc; xRm = xRc; pLm = pLc; pCm = pCc; pRm = pRc;
            xLc = xLp; xCc = xCp; xRc = xRp; pLc = pLp; pCc = pCp; pRc = pRp;
        }
    }
}

extern "C" void kernel_launch(void* const* d_in, const int* in_sizes, int n_in,
                              void* d_out, int out_size, void* d_ws, size_t ws_size,
                              hipStream_t stream) {
    const float* y0     = (const float*)d_in[1];
    const int*   env    = (const int*)d_in[2];
    const float* params = (const float*)d_in[4];
    const float* domain = (const float*)d_in[5];
    float* out = (float*)d_out;
    float* ws  = (float*)d_ws;   // 101,152 B used

    setup_tables<<<dim3(163), dim3(256), 0, stream>>>(ws, domain);
    turb_kernel<<<dim3(4096), dim3(512), 0, stream>>>(y0, env, params, domain, ws, out);
}

// Round 6
// 179.943 us; speedup vs baseline: 1.0422x; 1.0297x over previous
//
#include <hip/hip_runtime.h>
#include <math.h>

// Turb2dPDE, MFMA fp16-split pipeline. Per batch:
//   Y = x * C2; Out = F1 * Y; X = streams x G; psiT = Hc x X; then stencil.
// R1: 512-thread blocks.  R2/R3: SGPR addressing, const-offset stencil.
// R4: S32 restride->b128, Se dwordx4 layout.
// R5/R6: TWO BATCHES PER BLOCK (grid 2048, LDS 2x40448=80896, 2 blocks/CU).
//     Barriers per batch halve (6 -> 3); table fragments (TB1/TA2/TG/TH)
//     loaded once per position, used for both batches' MFMAs. Theory: the
//     kernel is bound by the waitcnt-drain at each __syncthreads, not by
//     any pipe (occupancy/VALU/LDS-op theories all measured null R1-R4).
//     R6 = R5 resubmitted after an infra-level container failure (audit
//     found no OOB/hang/limit violation; R2 showed the same flake signature).

typedef _Float16 half8 __attribute__((ext_vector_type(8)));
typedef _Float16 half4 __attribute__((ext_vector_type(4)));
typedef float floatx4 __attribute__((ext_vector_type(4)));

#define WPI 0.09666439165562847f   // 2*pi/65

// half-unit offsets in ws
#define H_TB1 0        // [20 chunks][512] S1-B
#define H_TA2 10240    // [20 chunks][512] S2-A
#define H_TG  20480    // [12 chunks][512] S4a-B
#define H_TH  26624    // [12 chunks][512] S4b-A
// float-unit offsets
#define F_GR32 16384
#define F_GI32 16432
#define F_HC32 16480
#define F_HS32 16528
#define F_SE   16576   // [8][33] jj=32 col, then [8][33][32] grid
#define F_SEG  (F_SE + 264)

// per-batch LDS arena offsets (bytes), arena t at lds_raw + t*40448
#define ARENA 40448
#define OFF_YT   0
#define OFF_XR   0
#define OFF_XI   9216
#define OFF_X32R 18432
#define OFF_X32I 18688
#define OFF_ST   18944
#define OFF_S32  37952      // [4][36] f32
#define OFF_PSIT 18944

__device__ __forceinline__ float trig65(int t, int isSin) {
    return isSin ? __sinf(WPI * (float)t) : __cosf(WPI * (float)t);
}

__global__ void setup_tables(float* __restrict__ ws, const float* __restrict__ domain) {
    int idx = blockIdx.x * 256 + threadIdx.x;
    _Float16* tbH = (_Float16*)ws;
    const float inv = 1.0f / 4225.0f;
    if (idx < 32768) {
        float v = 0.0f;
        int part;
        if (idx < 10240) {                  // TB1 (B-layout): chunk=(ni*2+kc)*2+part
            int chunk = idx >> 9, within = idx & 511;
            part = chunk & 1; int kc = (chunk >> 1) & 1, ni = chunk >> 2;
            int l2 = within >> 3, j = within & 7;
            int row = 16 * ni + (l2 & 15);
            int k = 32 * kc + 8 * (l2 >> 4) + j;
            if (row < 66) {
                int c = (row < 32) ? row : (row < 64 ? row - 32 : 32);
                int isS = (row < 32) ? 0 : (row < 64 ? 1 : row - 64);
                v = trig65((k * c) % 65, isS);
                if (k == 0) v += trig65((64 * c) % 65, isS);
            }
        } else if (idx < 20480) {           // TA2 (A-layout): chunk=(mi*2+kc)*2+part
            int i2 = idx - 10240;
            int chunk = i2 >> 9, within = i2 & 511;
            part = chunk & 1; int kc = (chunk >> 1) & 1, mi = chunk >> 2;
            int l2 = within >> 3, j = within & 7;
            int row = 16 * mi + (l2 & 15);
            int m = 32 * kc + 8 * (l2 >> 4) + j;
            if (row < 66) {
                int jr = (row < 32) ? row : (row < 64 ? row - 32 : 32);
                int isS = (row < 32) ? 0 : (row < 64 ? 1 : row - 64);
                float s = isS ? 1.0f : -1.0f;   // P rows = -cos, Q rows = +sin
                v = s * trig65((jr * m) % 65, isS);
                if (m == 0) v += s * trig65((jr * 64) % 65, isS);
            }
        } else if (idx < 26624) {           // TG: chunk=(si*2+g)*2+part
            int i2 = idx - 20480;
            int chunk = i2 >> 9, within = i2 & 511;
            part = chunk & 1; int g = (chunk >> 1) & 1, si = chunk >> 2;
            int l2 = within >> 3, j = within & 7;
            int s = 16 * si + (l2 & 15);
            int jj = 8 * (l2 >> 4) + j;
            if (s <= 32) v = trig65((s * jj) % 65, g);
        } else {                            // TH: chunk=(pi*2+h)*2+part
            int i2 = idx - 26624;
            int chunk = i2 >> 9, within = i2 & 511;
            part = chunk & 1; int h = (chunk >> 1) & 1, pi2 = chunk >> 2;
            int l2 = within >> 3, j = within & 7;
            int p = 16 * pi2 + (l2 & 15);
            int c = 8 * (l2 >> 4) + j;
            if (p <= 32) {
                if (c == 0) v = h ? 0.0f : inv;
                else v = 2.0f * inv * trig65((c * p) % 65, h);
            }
        }
        _Float16 hh = (_Float16)v;
        tbH[idx] = part ? (_Float16)(v - (float)hh) : hh;
    } else if (idx < 32960) {               // fp32 aux
        int i2 = idx - 32768;
        int grp = i2 / 48, s = i2 - grp * 48;
        float v = 0.0f;
        if (s <= 32) {
            int t = (32 * s) % 65;
            float cs = __cosf(WPI * t), sn = __sinf(WPI * t);
            v = (grp == 0) ? cs : (grp == 1) ? sn : (grp == 2) ? 2.0f * inv * cs : 2.0f * inv * sn;
        }
        ws[F_GR32 + i2] = v;
    } else if (idx < 41672) {               // Se
        int i2 = idx - 32960;
        const float DX0 = 0.04908738521234052f;
        int e2, a, b2;
        if (i2 < 264) { e2 = i2 / 33; a = i2 - e2 * 33; b2 = 32; }
        else {
            int i3 = i2 - 264;
            e2 = i3 / 1056;
            int rem = i3 - e2 * 1056;
            a = rem >> 5; b2 = rem & 31;
        }
        float fdx = domain[e2] * DX0;
        float tt = 6.283185307179586f / (65.0f * fdx);
        float s2v = tt * tt;
        ws[F_SE + i2] = -1.0f / (1e-12f + s2v * (float)(a * a + b2 * b2));
    }
}

#define MFMA16(A, B, C) __builtin_amdgcn_mfma_f32_16x16x32_f16((A), (B), (C), 0, 0, 0)

__global__ __launch_bounds__(512, 4)
void turb_kernel(const float* __restrict__ y0, const int* __restrict__ env,
                 const float* __restrict__ params, const float* __restrict__ domain,
                 const float* __restrict__ ws, float* __restrict__ out) {
    __shared__ __align__(16) char lds_raw[2 * ARENA];

    const int b0 = blockIdx.x * 2, tid = threadIdx.x;
    const int wid = __builtin_amdgcn_readfirstlane(tid >> 6);
    const int lane = tid & 63, n16 = lane & 15, q = lane >> 4;
    const int lane8 = lane * 8;
    const _Float16* tbH = (const _Float16*)ws;
    const float* tf = ws;

    // per-batch scalars
    const int eA0 = __builtin_amdgcn_readfirstlane(env[b0]);
    const int eA1 = __builtin_amdgcn_readfirstlane(env[b0 + 1]);
    const float* SegA[2] = {tf + F_SEG + eA0 * 1056, tf + F_SEG + eA1 * 1056};
    const float* Se3A[2] = {tf + F_SE + eA0 * 33,   tf + F_SE + eA1 * 33};
    const float* xA[2]   = {y0 + (size_t)b0 * 4096,  y0 + (size_t)(b0 + 1) * 4096};
    float* outA[2]       = {out + (size_t)b0 * 4096, out + (size_t)(b0 + 1) * 4096};
    const float DX0 = 0.04908738521234052f;
    float invfA[2], inv12A[2];
    {
        float mu0 = params[2 * eA0], mu1 = params[2 * eA1];
        float f0 = domain[eA0] * DX0, f1 = domain[eA1] * DX0;
        float f02 = f0 * f0, f12 = f1 * f1;
        inv12A[0] = 1.0f / (12.0f * f02); invfA[0] = mu0 / f02;
        inv12A[1] = 1.0f / (12.0f * f12); invfA[1] = mu1 / f12;
    }

    // ---- S1: Yt[c'][m] = sum_k x[m][k]*TB1[c'][k], both batches per position
    {
        const int mi = wid & 3;
        half8 Ah[2][2], Al[2][2];
        #pragma unroll
        for (int t = 0; t < 2; t++) {
            const float* xrow = xA[t] + (16 * mi + n16) * 64 + 8 * q;
            #pragma unroll
            for (int kc = 0; kc < 2; kc++) {
                float4 v0 = *(const float4*)(xrow + 32 * kc);
                float4 v1 = *(const float4*)(xrow + 32 * kc + 4);
                float vv[8] = {v0.x, v0.y, v0.z, v0.w, v1.x, v1.y, v1.z, v1.w};
                #pragma unroll
                for (int u = 0; u < 8; u++) {
                    _Float16 h = (_Float16)vv[u];
                    Ah[t][kc][u] = h; Al[t][kc][u] = (_Float16)(vv[u] - (float)h);
                }
            }
        }
        const int niBeg = (wid & 4) ? 3 : 0;
        const int niEnd = (wid & 4) ? 5 : 3;
        for (int ni = niBeg; ni < niEnd; ni++) {
            const _Float16* tb = tbH + H_TB1 + ni * 2048 + lane8;
            half8 B0h = *(const half8*)(tb);
            half8 B0l = *(const half8*)(tb + 512);
            half8 B1h = *(const half8*)(tb + 1024);
            half8 B1l = *(const half8*)(tb + 1536);
            const int cp = 16 * ni + n16;
            const bool st = (ni < 4 || n16 < 2);
            #pragma unroll
            for (int t = 0; t < 2; t++) {
                floatx4 acc = {0.f, 0.f, 0.f, 0.f};
                acc = MFMA16(Ah[t][0], B0h, acc); acc = MFMA16(Ah[t][0], B0l, acc); acc = MFMA16(Al[t][0], B0h, acc);
                acc = MFMA16(Ah[t][1], B1h, acc); acc = MFMA16(Ah[t][1], B1l, acc); acc = MFMA16(Al[t][1], B1h, acc);
                if (st) {
                    half4 hh, ll;
                    #pragma unroll
                    for (int i = 0; i < 4; i++) {
                        _Float16 h = (_Float16)acc[i];
                        hh[i] = h; ll[i] = (_Float16)(acc[i] - (float)h);
                    }
                    _Float16* Yt = (_Float16*)(lds_raw + t * ARENA + OFF_YT);
                    *(half4*)(Yt + cp * 136 + 16 * mi + 4 * q) = hh;
                    *(half4*)(Yt + cp * 136 + 64 + 16 * mi + 4 * q) = ll;
                }
            }
        }
    }
    __syncthreads();

    // ---- S2: streams; tables loaded once per position, both batches consume
    for (int pos = wid; pos < 25; pos += 8) {
        const int mi = pos / 5, ni = pos - 5 * mi;
        const _Float16* ta = tbH + H_TA2 + mi * 2048 + lane8;
        half8 Ah0 = *(const half8*)(ta);
        half8 Al0 = *(const half8*)(ta + 512);
        half8 Ah1 = *(const half8*)(ta + 1024);
        half8 Al1 = *(const half8*)(ta + 1536);
        const int yoff = (16 * ni + n16) * 136 + 8 * q;
        const int cp = 16 * ni + n16;
        const int cc = (ni == 4) ? 32 : (cp & 31);
        const int isS = (ni == 4) ? n16 : (ni >> 1);
        const bool valid = (ni < 4) || (n16 < 2);
        #pragma unroll
        for (int t = 0; t < 2; t++) {
            const _Float16* Yt = (const _Float16*)(lds_raw + t * ARENA + OFF_YT);
            const _Float16* yrow = Yt + yoff;
            half8 Bh0 = *(const half8*)(yrow);
            half8 Bl0 = *(const half8*)(yrow + 64);
            half8 Bh1 = *(const half8*)(yrow + 32);
            half8 Bl1 = *(const half8*)(yrow + 96);
            floatx4 acc = {0.f, 0.f, 0.f, 0.f};
            acc = MFMA16(Ah0, Bh0, acc); acc = MFMA16(Ah0, Bl0, acc); acc = MFMA16(Al0, Bh0, acc);
            acc = MFMA16(Ah1, Bh1, acc); acc = MFMA16(Ah1, Bl1, acc); acc = MFMA16(Al1, Bh1, acc);
            if (valid) {
                _Float16* ST = (_Float16*)(lds_raw + t * ARENA + OFF_ST);
                float* S32 = (float*)(lds_raw + t * ARENA + OFF_S32);
                if (mi < 4) {
                    const int isQ = mi >> 1;
                    const int sid = isQ ? (isS ? 3 : 1) : (isS ? 2 : 0);
                    const int jjb = 16 * (mi & 1) + 4 * q;
                    floatx4 Sv = *(const floatx4*)(SegA[t] + cc * 32 + jjb);
                    float ssg = (sid == 2) ? -2.0f : 2.0f;
                    half4 hh, ll;
                    #pragma unroll
                    for (int i = 0; i < 4; i++) {
                        float v = ssg * Sv[i] * acc[i];
                        _Float16 h = (_Float16)v;
                        hh[i] = h; ll[i] = (_Float16)(v - (float)h);
                    }
                    _Float16* sb = ST + sid * 2376 + cc * 72 + jjb;
                    *(half4*)sb = hh;
                    *(half4*)(sb + 32) = ll;
                } else if (q == 0) {            // rows 64 (P32) / 65 (Q32) -> S32
                    float S = Se3A[t][cc];
                    #pragma unroll
                    for (int i = 0; i < 2; i++) {
                        int sid = i ? (isS ? 3 : 1) : (isS ? 2 : 0);
                        float v = 2.0f * S * acc[i];
                        if (sid == 2) v = -v;
                        S32[sid * 36 + cc] = v;
                    }
                }
            }
        }
    }
    __syncthreads();

    // ---- j=0 fixup: wave t handles batch t, lanes 0..32
    if (wid < 2 && lane < 33) {
        _Float16* ST = (_Float16*)(lds_raw + wid * ARENA + OFF_ST);
        const int c = lane;
        float v0[4];
        #pragma unroll
        for (int sid = 0; sid < 4; sid++)
            v0[sid] = (float)ST[sid * 2376 + c * 72] + (float)ST[sid * 2376 + c * 72 + 32];
        float pr = 0.5f * (v0[0] + v0[3]), pi = 0.5f * (v0[1] + v0[2]);
        if (c == 0) { pr = 0.f; pi = 0.f; }
        float outs[4] = {pr, pi, pi, pr};
        #pragma unroll
        for (int sid = 0; sid < 4; sid++) {
            _Float16 h = (_Float16)outs[sid];
            ST[sid * 2376 + c * 72] = h;
            ST[sid * 2376 + c * 72 + 32] = (_Float16)(outs[sid] - (float)h);
        }
    }
    __syncthreads();

    // ---- S4a: 18 shared positions (ci, si, g); tables shared across batches
    for (int pos = wid; pos < 18; pos += 8) {
        const int ci = pos / 6, rem = pos - 6 * ci;
        const int si = rem >> 1, g = rem & 1;
        const _Float16* tg = tbH + H_TG + si * 2048 + lane8;
        half8 Grh = *(const half8*)(tg);
        half8 Grl = *(const half8*)(tg + 512);
        half8 Gih = *(const half8*)(tg + 1024);
        half8 Gil = *(const half8*)(tg + 1536);
        const int s = 16 * si + n16;
        const float ga = tf[F_GR32 + s], gi2 = tf[F_GI32 + s];
        const bool sval = (si < 2) || (n16 == 0);     // s <= 32
        const float sgn = g ? 1.0f : -1.0f;
        const int cb = 16 * ci + 4 * q;
        const int aoff = (2 * g) * 2376 + (16 * ci + n16) * 72 + 8 * q;
        #pragma unroll
        for (int t = 0; t < 2; t++) {
            const _Float16* ST = (const _Float16*)(lds_raw + t * ARENA + OFF_ST);
            const float* S32 = (const float*)(lds_raw + t * ARENA + OFF_S32);
            const _Float16* st0 = ST + aoff;
            half8 A0h = *(const half8*)(st0),        A0l = *(const half8*)(st0 + 32);
            half8 A1h = *(const half8*)(st0 + 2376), A1l = *(const half8*)(st0 + 2376 + 32);
            floatx4 aA = {0.f,0.f,0.f,0.f}, aB = aA;
            aA = MFMA16(A0h, Grh, aA); aA = MFMA16(A0h, Grl, aA); aA = MFMA16(A0l, Grh, aA);
            aB = MFMA16(A1h, Gih, aB); aB = MFMA16(A1h, Gil, aB); aB = MFMA16(A1l, Gih, aB);
            _Float16* Xo = (_Float16*)(lds_raw + t * ARENA + (g ? OFF_XI : OFF_XR));
            float* X32o = (float*)(lds_raw + t * ARENA + (g ? OFF_X32I : OFF_X32R));
            if (ci < 2) {
                floatx4 U0 = *(const floatx4*)(S32 + (2 * g) * 36 + cb);
                floatx4 U1 = *(const floatx4*)(S32 + (2 * g + 1) * 36 + cb);
                half4 hP, lP, hM, lM;
                #pragma unroll
                for (int i = 0; i < 4; i++) {
                    float av = aA[i] + ga * U0[i], bv = aB[i] + gi2 * U1[i];
                    float xP = av + sgn * bv;
                    float xM = av - sgn * bv;
                    _Float16 h;
                    h = (_Float16)xP; hP[i] = h; lP[i] = (_Float16)(xP - (float)h);
                    h = (_Float16)xM; hM[i] = h; lM[i] = (_Float16)(xM - (float)h);
                }
                if (sval) {
                    *(half4*)(Xo + s * 72 + cb) = hP;  *(half4*)(Xo + s * 72 + 32 + cb) = lP;
                    if (s >= 2) {
                        int sm = 65 - s;
                        *(half4*)(Xo + sm * 72 + cb) = hM;  *(half4*)(Xo + sm * 72 + 32 + cb) = lM;
                    }
                }
            } else if (q == 0 && sval) {            // c = 32 column -> fp32
                float u0 = S32[(2 * g) * 36 + 32], u1 = S32[(2 * g + 1) * 36 + 32];
                float av = aA[0] + ga * u0, bv = aB[0] + gi2 * u1;
                X32o[s] = av + sgn * bv;
                if (s >= 2) X32o[65 - s] = av - sgn * bv;
            }
        }
    }
    __syncthreads();

    // ---- S4b: 24 single-batch positions for exact 3/wave balance
    for (int p24 = wid; p24 < 24; p24 += 8) {
        const int t = p24 / 12;
        const int pos = p24 - 12 * t;
        const int ri = pos / 3, pti = pos - 3 * ri;
        const char* base = lds_raw + t * ARENA;
        const _Float16* Xr = (const _Float16*)(base + OFF_XR);
        const _Float16* Xi = (const _Float16*)(base + OFF_XI);
        const float* X32r = (const float*)(base + OFF_X32R);
        const float* X32i = (const float*)(base + OFF_X32I);
        float* psiT = (float*)(base + OFF_PSIT);
        const int brow = (16 * ri + n16) * 72 + 8 * q;
        half8 Brh = *(const half8*)(Xr + brow), Brl = *(const half8*)(Xr + brow + 32);
        half8 Bih = *(const half8*)(Xi + brow), Bil = *(const half8*)(Xi + brow + 32);
        const _Float16* th = tbH + H_TH + pti * 2048 + lane8;
        half8 Hch = *(const half8*)(th);
        half8 Hcl = *(const half8*)(th + 512);
        half8 Hsh = *(const half8*)(th + 1024);
        half8 Hsl = *(const half8*)(th + 1536);
        floatx4 aE = {0.f,0.f,0.f,0.f}, aF = aE;
        aE = MFMA16(Hch, Brh, aE); aE = MFMA16(Hch, Brl, aE); aE = MFMA16(Hcl, Brh, aE);
        aF = MFMA16(Hsh, Bih, aF); aF = MFMA16(Hsh, Bil, aF); aF = MFMA16(Hsl, Bih, aF);
        const int r = 16 * ri + n16;
        float xr32 = X32r[r], xi32 = X32i[r];
        if (pti < 2) {
            const int pb = 16 * pti + 4 * q;
            floatx4 Hc4 = *(const floatx4*)(tf + F_HC32 + pb);
            floatx4 Hs4 = *(const floatx4*)(tf + F_HS32 + pb);
            float* pp = psiT + pb * 65 + r;
            float* pm = psiT + (65 - pb) * 65 + r;
            #pragma unroll
            for (int i = 0; i < 4; i++) {
                float E = aE[i] + xr32 * Hc4[i];
                float F = aF[i] + xi32 * Hs4[i];
                pp[i * 65] = E - F;
                if (pb + i >= 2) pm[-i * 65] = E + F;
            }
        } else if (q == 0) {                    // p == 32
            float E = aE[0] + xr32 * tf[F_HC32 + 32];
            float F = aF[0] + xi32 * tf[F_HS32 + 32];
            psiT[32 * 65 + r] = E - F;
            psiT[33 * 65 + r] = E + F;
        }
    }
    __syncthreads();

    // ---- stencil: both batches, lane=c, rows 8*wid..+7 each
    #pragma unroll
    for (int t = 0; t < 2; t++) {
        const float* psiT = (const float*)(lds_raw + t * ARENA + OFF_PSIT);
        const float* x0 = xA[t];
        const float inv12 = inv12A[t], invf = invfA[t];
        const int c = lane;
        const int cm1 = (c + 63) & 63, cp1 = (c + 1) & 63;
        const int r0 = wid * 8;
        const float* xL = x0 + r0 * 64 + cm1;
        const float* xC = x0 + r0 * 64 + c;
        const float* xR = x0 + r0 * 64 + cp1;
        const float* pL = psiT + cm1 * 65 + r0;
        const float* pC = psiT + c * 65 + r0;
        const float* pR = psiT + cp1 * 65 + r0;
        float* ob = outA[t] + r0 * 64 + c;
        const int mo = (wid == 0) ? 63 : -1;    // prev-row offset (wraps for wid 0)
        float xLm = xL[mo * 64], xCm = xC[mo * 64], xRm = xR[mo * 64];
        float pLm = pL[mo], pCm = pC[mo], pRm = pR[mo];
        float xLc = xL[0], xCc = xC[0], xRc = xR[0];
        float pLc = pL[0], pCc = pC[0], pRc = pR[0];
        #pragma unroll
        for (int it = 0; it < 8; it++) {
            int ro = it + 1;
            if (it == 7 && wid == 7) ro = -56;  // next-row wrap (uniform, last iter only)
            float xLp = xL[ro * 64], xCp = xC[ro * 64], xRp = xR[ro * 64];
            float pLp = pL[ro], pCp = pC[ro], pRp = pR[ro];
            float J1 = (pCp - pCm) * (xRc - xLc) - (pRc - pLc) * (xCp - xCm);
            float J2 = xRc * (pRp - pRm) - xLc * (pLp - pLm) - xCp * (pRp - pLp) + xCm * (pRm - pLm);
            float J3 = xRp * (pCp - pRc) - xLm * (pLc - pCm) - xLp * (pCp - pLc) + xRm * (pRc - pCm);
            float lap = xCm + xLc - 4.f * xCc + xRc + xLp + xCp;
            ob[it * 64] = -(J1 + J2 + J3) * inv12 + lap * invf;
            xLm = xLc; xCm = xCc; xRm = xRc; pLm = pLc; pCm = pCc; pRm = pRc;
            xLc = xLp; xCc = xCp; xRc = xRp; pLc = pLp; pCc = pCp; pRc = pRp;
        }
    }
}

extern "C" void kernel_launch(void* const* d_in, const int* in_sizes, int n_in,
                              void* d_out, int out_size, void* d_ws, size_t ws_size,
                              hipStream_t stream) {
    const float* y0     = (const float*)d_in[1];
    const int*   env    = (const int*)d_in[2];
    const float* params = (const float*)d_in[4];
    const float* domain = (const float*)d_in[5];
    float* out = (float*)d_out;
    float* ws  = (float*)d_ws;   // 101,152 B used

    setup_tables<<<dim3(163), dim3(256), 0, stream>>>(ws, domain);
    turb_kernel<<<dim3(2048), dim3(512), 0, stream>>>(y0, env, params, domain, ws, out);
}